// Round 9
// baseline (120.769 us; speedup 1.0000x reference)
//
#include <hip/hip_runtime.h>
#include <hip/hip_bf16.h>

#define BB 128
#define NN 512
#define ALPHA_ 0.2f
#define NEG_INF_ -9.0e15f
#define SPB 536   // bf16 prob-row stride: 268 dwords ≡ 12 mod 32 → ≤2-way conflict on A-frag reads

typedef short bf16x8 __attribute__((ext_vector_type(8)));
typedef float f32x4  __attribute__((ext_vector_type(4)));

__device__ __forceinline__ float bf2f(__hip_bfloat16 v) { return __bfloat162float(v); }

// k0: (blocks 0..127) pack adj into bitmask; (blocks 128..159) convert W to bf16
// in MFMA B-layout: Wb[mat][f][c] (so k1 B-frags load straight from global).
__global__ __launch_bounds__(256) void k0_prep(const int* __restrict__ adj,
                                               const float* __restrict__ W,
                                               unsigned char* __restrict__ bits,
                                               unsigned short* __restrict__ Wb) {
    if (blockIdx.x < 128) {
        int idx = blockIdx.x * 256 + threadIdx.x;     // 0..32767
        const int* p = adj + (size_t)idx * 8;
        unsigned m = 0;
        #pragma unroll
        for (int t = 0; t < 8; ++t) m |= (p[t] > 0 ? 1u : 0u) << t;
        bits[idx] = (unsigned char)m;
    } else {
        int gid = (blockIdx.x - 128) * 256 + threadIdx.x;  // 0..8191
        int mat = gid >> 12, rem = gid & 4095;
        int f = rem >> 6, c = rem & 63;
        __hip_bfloat16 v = __float2bfloat16(W[mat * 4096 + c * 64 + f]);
        Wb[mat * 4096 + f * 64 + c] = *(unsigned short*)&v;
    }
}

// k1 (MFMA, no staging LDS): block = (b, 64-node tile). A-frags built directly from
// global x (coalesced fp32->bf16); B-frags directly from global Wb (L2 broadcast).
// h0 -> d_out fp32; h1 -> LDS transpose -> h1T[b][f][n]; s1/s2 from fp32 accs.
__global__ __launch_bounds__(256, 2) void k1_proj(
    const float* __restrict__ x, const unsigned short* __restrict__ Wb,
    const float* __restrict__ a,
    __hip_bfloat16* __restrict__ h1T, float* __restrict__ h0out,
    float* __restrict__ s1, float* __restrict__ s2)
{
    __shared__ unsigned short sT[64 * 66];            // h1 transpose [f][n_local]
    int tid = threadIdx.x, lane = tid & 63, w = tid >> 6;
    int lane15 = lane & 15, quad = lane >> 4;
    int b = blockIdx.x >> 3, n0 = (blockIdx.x & 7) << 6;

    // B-frags: Wb[mat][nt*16+lane15][kt*32+quad*8 .. +7], 16 frags in VGPRs
    bf16x8 bfr[2][4][2];
    #pragma unroll
    for (int mat = 0; mat < 2; ++mat)
        #pragma unroll
        for (int nt = 0; nt < 4; ++nt)
            #pragma unroll
            for (int kt = 0; kt < 2; ++kt)
                bfr[mat][nt][kt] = *(const bf16x8*)(Wb + mat * 4096 + (nt * 16 + lane15) * 64 + kt * 32 + quad * 8);

    // A-frags from global x + MFMA
    int myrow = b * NN + n0 + w * 16 + lane15;        // m = lane15, stripe base w*16
    f32x4 acc0[4] = {{0,0,0,0},{0,0,0,0},{0,0,0,0},{0,0,0,0}};
    f32x4 acc1[4] = {{0,0,0,0},{0,0,0,0},{0,0,0,0},{0,0,0,0}};
    #pragma unroll
    for (int kt = 0; kt < 2; ++kt) {
        const float* xp = x + (size_t)myrow * 64 + kt * 32 + quad * 8;
        float4 v0 = *(const float4*)(xp + 0);
        float4 v1 = *(const float4*)(xp + 4);
        union { bf16x8 v; __hip_bfloat16 h[8]; } af;
        af.h[0] = __float2bfloat16(v0.x); af.h[1] = __float2bfloat16(v0.y);
        af.h[2] = __float2bfloat16(v0.z); af.h[3] = __float2bfloat16(v0.w);
        af.h[4] = __float2bfloat16(v1.x); af.h[5] = __float2bfloat16(v1.y);
        af.h[6] = __float2bfloat16(v1.z); af.h[7] = __float2bfloat16(v1.w);
        #pragma unroll
        for (int nt = 0; nt < 4; ++nt) {
            acc0[nt] = __builtin_amdgcn_mfma_f32_16x16x32_bf16(af.v, bfr[0][nt][kt], acc0[nt], 0, 0, 0);
            acc1[nt] = __builtin_amdgcn_mfma_f32_16x16x32_bf16(af.v, bfr[1][nt][kt], acc1[nt], 0, 0, 0);
        }
    }

    // epilogue: D[m = quad*4+r][f = nt*16+lane15], row = n0 + w*16 + quad*4 + r
    float a1v[4], a2v[4];
    #pragma unroll
    for (int nt = 0; nt < 4; ++nt) {
        a1v[nt] = a[nt * 16 + lane15];
        a2v[nt] = a[64 + nt * 16 + lane15];
    }
    float p1[4] = {0, 0, 0, 0}, p2[4] = {0, 0, 0, 0};
    #pragma unroll
    for (int nt = 0; nt < 4; ++nt) {
        #pragma unroll
        for (int r = 0; r < 4; ++r) {
            int nl = w * 16 + quad * 4 + r;
            int f  = nt * 16 + lane15;
            float h0v = acc0[nt][r], h1v = acc1[nt][r];
            h0out[((size_t)b * NN + n0 + nl) * 64 + f] = h0v;
            __hip_bfloat16 hb = __float2bfloat16(h1v);
            sT[f * 66 + nl] = *(unsigned short*)&hb;
            float hs = h0v + h1v;
            p1[r] = fmaf(hs, a1v[nt], p1[r]);
            p2[r] = fmaf(hs, a2v[nt], p2[r]);
        }
    }
    #pragma unroll
    for (int r = 0; r < 4; ++r) {
        float v1 = p1[r], v2 = p2[r];
        #pragma unroll
        for (int o = 1; o < 16; o <<= 1) {
            v1 += __shfl_xor(v1, o, 64);
            v2 += __shfl_xor(v2, o, 64);
        }
        if (lane15 == 0) {
            int row = b * NN + n0 + w * 16 + quad * 4 + r;
            s1[row] = v1; s2[row] = v2;
        }
    }
    __syncthreads();
    // h1T: wave w writes f-rows w*16..w*16+15, 128B contiguous per store
    unsigned short* h1Tu = (unsigned short*)h1T;
    #pragma unroll
    for (int fr = 0; fr < 16; ++fr) {
        int f = w * 16 + fr;
        h1Tu[(size_t)b * 32768 + f * 512 + n0 + lane] = sT[f * 66 + lane];
    }
}

// k2: block = (b, 32 rows). Wave w: softmax rows 8w..8w+7 (bitmask adj, reg-cached s2),
// diag prob zeroed pre-MFMA (saved to sPi). MFMA: 8-deep B-frag register prefetch,
// B shared across 2 m-tiles. Epilogue: out = acc*inv + pi*inv*h0 + bias (no scatter).
__global__ __launch_bounds__(256, 2) void k2_att(
    const unsigned char* __restrict__ adjbits,
    const float* __restrict__ bias,
    const __hip_bfloat16* __restrict__ h1T,
    const float* __restrict__ s1, const float* __restrict__ s2,
    float* __restrict__ out)          // holds h0 on entry
{
    __shared__ __align__(16) __hip_bfloat16 sPb[32 * SPB];   // 34.3 KB
    __shared__ float sInv[32], sPi[32];
    int tid = threadIdx.x, w = tid >> 6, lane = tid & 63;
    int b = blockIdx.y, i0 = blockIdx.x * 32;

    const float* s2b = s2 + (size_t)b * NN;
    float4 q0 = *(const float4*)(s2b + lane * 8);
    float4 q1 = *(const float4*)(s2b + lane * 8 + 4);
    float sv[8] = {q0.x, q0.y, q0.z, q0.w, q1.x, q1.y, q1.z, q1.w};

    for (int r2 = 0; r2 < 8; ++r2) {
        int r = 8 * w + r2;
        int i = i0 + r;
        float s1i = s1[(size_t)b * NN + i];
        unsigned mb = adjbits[(size_t)i * 64 + lane];
        float e[8];
        #pragma unroll
        for (int t = 0; t < 8; ++t) {
            float s = s1i + sv[t];
            s = fmaxf(s, ALPHA_ * s);             // leaky-relu
            e[t] = (mb & (1u << t)) ? s : NEG_INF_;
        }
        float lm = fmaxf(fmaxf(fmaxf(e[0], e[1]), fmaxf(e[2], e[3])),
                         fmaxf(fmaxf(e[4], e[5]), fmaxf(e[6], e[7])));
        #pragma unroll
        for (int o = 32; o > 0; o >>= 1) lm = fmaxf(lm, __shfl_xor(lm, o, 64));
        float p[8], ls = 0.f;
        #pragma unroll
        for (int t = 0; t < 8; ++t) { p[t] = __expf(e[t] - lm); ls += p[t]; }
        #pragma unroll
        for (int o = 32; o > 0; o >>= 1) ls += __shfl_xor(ls, o, 64);
        if (lane == 0) sInv[r] = 1.f / ls;
        if ((i >> 3) == lane) {                   // lane owning j == i
            sPi[r] = p[i & 7];                    // save diag prob (fp32)
            p[i & 7] = 0.f;                       // exclude diag from MFMA
        }
        union { bf16x8 v; __hip_bfloat16 h[8]; } pk;
        #pragma unroll
        for (int t = 0; t < 8; ++t) pk.h[t] = __float2bfloat16(p[t]);
        *(bf16x8*)&sPb[r * SPB + lane * 8] = pk.v;
    }
    __syncthreads();

    // MFMA: wave w = f-tile; two m-tiles (rows 0..15, 16..31) share B-frags
    int lane15 = lane & 15, quad = lane >> 4;
    int n0w = w * 16;
    const __hip_bfloat16* h1b = h1T + (size_t)b * 32768;
    const __hip_bfloat16* bptr = h1b + (size_t)(n0w + lane15) * 512 + quad * 8;
    const __hip_bfloat16* aptr0 = &sPb[lane15 * SPB + quad * 8];
    const __hip_bfloat16* aptr1 = &sPb[(16 + lane15) * SPB + quad * 8];
    f32x4 acc0 = {0, 0, 0, 0}, acc1 = {0, 0, 0, 0};
    bf16x8 bfr[8];
    #pragma unroll
    for (int half = 0; half < 2; ++half) {
        #pragma unroll
        for (int g = 0; g < 8; ++g)
            bfr[g] = *(const bf16x8*)(bptr + (half * 8 + g) * 32);
        #pragma unroll
        for (int g = 0; g < 8; ++g) {
            int kt = half * 8 + g;
            bf16x8 a0 = *(const bf16x8*)(aptr0 + kt * 32);
            acc0 = __builtin_amdgcn_mfma_f32_16x16x32_bf16(a0, bfr[g], acc0, 0, 0, 0);
            bf16x8 a1 = *(const bf16x8*)(aptr1 + kt * 32);
            acc1 = __builtin_amdgcn_mfma_f32_16x16x32_bf16(a1, bfr[g], acc1, 0, 0, 0);
        }
    }

    // Epilogue: out = acc*inv + pi*inv*h0 + bias  (diag already excluded from acc)
    int f = n0w + lane15;
    float biasf = bias[f];
    #pragma unroll
    for (int t = 0; t < 2; ++t) {
        f32x4 ac = t ? acc1 : acc0;
        #pragma unroll
        for (int r = 0; r < 4; ++r) {
            int m = t * 16 + quad * 4 + r;
            int i = i0 + m;
            size_t oidx = ((size_t)b * NN + i) * 64 + f;
            float h0v = out[oidx];
            float inv = sInv[m], pi = sPi[m];
            out[oidx] = ac[r] * inv + pi * inv * h0v + biasf;
        }
    }
}

extern "C" void kernel_launch(void* const* d_in, const int* in_sizes, int n_in,
                              void* d_out, int out_size, void* d_ws, size_t ws_size,
                              hipStream_t stream) {
    const void* p_x = nullptr; const void* p_adj = nullptr; const void* p_W = nullptr;
    const void* p_a = nullptr; const void* p_bias = nullptr;
    for (int k = 0; k < n_in; ++k) {
        switch (in_sizes[k]) {
            case 128 * 512 * 64: p_x    = d_in[k]; break;
            case 512 * 512:      p_adj  = d_in[k]; break;
            case 2 * 64 * 64:    p_W    = d_in[k]; break;
            case 2 * 64:         p_a    = d_in[k]; break;
            case 64:             p_bias = d_in[k]; break;
        }
    }
    const float* x    = (const float*)p_x;
    const int*   adj  = (const int*)p_adj;
    const float* W    = (const float*)p_W;
    const float* a    = (const float*)p_a;
    const float* bias = (const float*)p_bias;
    float* out = (float*)d_out;

    // ws (8.85 MB): h1T bf16 8MB | s1 256KB | s2 256KB | adjbits 32KB | Wb 16KB
    __hip_bfloat16* h1T = (__hip_bfloat16*)d_ws;
    float* s1 = (float*)((char*)d_ws + (8u << 20));
    float* s2 = s1 + 65536;
    unsigned char* adjbits = (unsigned char*)(s2 + 65536);
    unsigned short* Wb = (unsigned short*)(adjbits + 32768);

    k0_prep<<<dim3(160), 256, 0, stream>>>(adj, W, adjbits, Wb);
    k1_proj<<<dim3(BB * 8), 256, 0, stream>>>(x, Wb, a, h1T, out, s1, s2);
    k2_att<<<dim3(NN / 32, BB), 256, 0, stream>>>(adjbits, bias, h1T, s1, s2, out);
}